// Round 5
// baseline (114.563 us; speedup 1.0000x reference)
//
#include <hip/hip_runtime.h>

// Decoder: N=4096 LSTM seqs (K=16 x B=256), H=64, T=50, GMM head (GC=16, PD=2).
// Round 5: 3-kernel pipeline.
//  k0: pack weights (Wih/Wh0/Wc0/Whh/proj) into bf16 hi/lo MFMA B-frag layout in ws.
//  k1: LSTM recurrence only. 512 blocks x 256 thr x 8 samples (2 blocks/CU).
//      Duplicated A-rows (8..15 = samples 0..7) -> cell work spread over all lanes
//      (2 elems/lane). 24 MFMA + register cell + 1 barrier per step.
//      h_t stored to global as bf16-hi plane for k2.
//  k2: proj + GMM, fully parallel (1024 blocks), MFMA proj from packed frags,
//      in-lane GMM (4 comps/lane) + 2-stage shfl logsumexp, atomicAdd outputs.

#define T_ 50

typedef __attribute__((ext_vector_type(8))) short short8;
typedef __attribute__((ext_vector_type(4))) float f32x4;

#define MFMA(a, b, c) __builtin_amdgcn_mfma_f32_16x16x32_bf16(a, b, c, 0, 0, 0)

// ws layout: [0, 26214400) bytes: ushort H[t=50][n=4096][u=64] (bf16 hi of h_{t+1})
//            [26214400, +581632): packed frags (short8 slots)
#define HBYTES 26214400
#define WIH_B 0
#define WH0_B 20480
#define WC0_B 25600
#define WHH_B 30720
#define PRJ_B 34816

__device__ __forceinline__ float sigf(float x)  { return 1.0f / (1.0f + __expf(-x)); }
__device__ __forceinline__ float tanh_(float x) { return 1.0f - 2.0f / (__expf(2.0f * x) + 1.0f); }

__device__ __forceinline__ void splitf(float f, unsigned short& hi, unsigned short& lo) {
    unsigned b = __float_as_uint(f);
    hi = (unsigned short)(b >> 16);
    float fh = __uint_as_float(b & 0xffff0000u);
    lo = (unsigned short)(__float_as_uint(f - fh) >> 16);
}

__device__ __forceinline__ void pack8(const float* p, short8& hi, short8& lo) {
    #pragma unroll
    for (int e = 0; e < 8; ++e) {
        unsigned short h, l;
        splitf(p[e], h, l);
        hi[e] = (short)h; lo[e] = (short)l;
    }
}

// ---------------- k0: weight packing ----------------
__global__ void pack_kernel(const float* __restrict__ Wih, const float* __restrict__ Whh,
                            const float* __restrict__ Wh0, const float* __restrict__ Wc0,
                            const float* __restrict__ Wpi, const float* __restrict__ Wmu,
                            const float* __restrict__ Wls, const float* __restrict__ Wcorr,
                            short8* __restrict__ WF)
{
    int id = blockIdx.x * 256 + threadIdx.x;
    if (id >= 18176) return;
    const float* src;
    int dst0, dst1;
    if (id < 10240) {                               // Wih
        int ks = id >> 10, rem = id & 1023;
        int q = rem >> 8, rem2 = rem & 255;
        int w = rem2 >> 6, l = rem2 & 63;
        int g = l >> 4, c = l & 15;
        src = Wih + (q*64 + w*16 + c)*322 + ks*32 + g*8;
        dst0 = WIH_B + (((ks*4 + q)*2 + 0)*4 + w)*64 + l;
        dst1 = WIH_B + (((ks*4 + q)*2 + 1)*4 + w)*64 + l;
    } else if (id < 12800) {                        // Wh0
        int t2 = id - 10240;
        int ks = t2 >> 8, rem = t2 & 255;
        int w = rem >> 6, l = rem & 63;
        int g = l >> 4, c = l & 15;
        src = Wh0 + (w*16 + c)*320 + ks*32 + g*8;
        dst0 = WH0_B + ((ks*2 + 0)*4 + w)*64 + l;
        dst1 = WH0_B + ((ks*2 + 1)*4 + w)*64 + l;
    } else if (id < 15360) {                        // Wc0
        int t2 = id - 12800;
        int ks = t2 >> 8, rem = t2 & 255;
        int w = rem >> 6, l = rem & 63;
        int g = l >> 4, c = l & 15;
        src = Wc0 + (w*16 + c)*320 + ks*32 + g*8;
        dst0 = WC0_B + ((ks*2 + 0)*4 + w)*64 + l;
        dst1 = WC0_B + ((ks*2 + 1)*4 + w)*64 + l;
    } else if (id < 17408) {                        // Whh
        int t3 = id - 15360;
        int q = t3 >> 9, rem = t3 & 511;
        int ks = rem >> 8, rem2 = rem & 255;
        int w = rem2 >> 6, l = rem2 & 63;
        int g = l >> 4, c = l & 15;
        src = Whh + (q*64 + w*16 + c)*64 + ks*32 + g*8;
        dst0 = WHH_B + (((q*2 + ks)*2 + 0)*4 + w)*64 + l;
        dst1 = WHH_B + (((q*2 + ks)*2 + 1)*4 + w)*64 + l;
    } else {                                        // proj (6 tiles of 16 rows)
        int t4 = id - 17408;
        int pt = t4 >> 7, rem = t4 & 127;
        int ks = rem >> 6, l = rem & 63;
        int g = l >> 4, c = l & 15;
        int r3 = pt*16 + c;
        const float* p;
        if      (r3 < 16) p = Wpi   + r3*64;
        else if (r3 < 48) p = Wmu   + (r3-16)*64;
        else if (r3 < 80) p = Wls   + (r3-48)*64;
        else              p = Wcorr + (r3-80)*64;
        src = p + ks*32 + g*8;
        dst0 = PRJ_B + ((pt*2 + ks)*2 + 0)*64 + l;
        dst1 = PRJ_B + ((pt*2 + ks)*2 + 1)*64 + l;
    }
    short8 hi, lo;
    pack8(src, hi, lo);
    WF[dst0] = hi;
    WF[dst1] = lo;
}

// ---------------- k1: LSTM recurrence ----------------
__launch_bounds__(256, 2)
__global__ void lstm_kernel(
    const float* __restrict__ x,        const float* __restrict__ z,
    const float* __restrict__ inp_seqs, const float* __restrict__ pred_seqs,
    const float* __restrict__ Wih,      const float* __restrict__ bh0,
    const float* __restrict__ bc0,      const float* __restrict__ bih,
    const float* __restrict__ bhh,
    unsigned short* __restrict__ Hout,  const short8* __restrict__ WF)
{
    // floats: ZXL [0,2592) 8x324 (prologue) | HF at 2592 (2304 ushorts = 1152 f)
    //         FUT [3744,4544) 50x16 | PRS [4544,4560)
    __shared__ __align__(16) float smem[4560];
    float* ZXL = smem;
    unsigned short* HB = (unsigned short*)(smem + 2592);
    unsigned short* H0h = HB;
    unsigned short* H0l = HB + 576;
    unsigned short* H1h = HB + 1152;
    unsigned short* H1l = HB + 1728;
    float* FUT = smem + 3744;
    float* PRS = smem + 4544;

    const int j = threadIdx.x;
    const int w = j >> 6;     // wave 0..3
    const int l = j & 63;
    const int g = l >> 4;
    const int c = l & 15;
    const int U = w*16 + c;   // unit column this lane owns
    const int blk = blockIdx.x;

    // ---- fill ZXL (8 samples x 320), FUT, PRS
    for (int e = j; e < 8*320; e += 256) {
        int s = e / 320, k = e - s*320;
        int n = blk*8 + s, kk = n >> 8, b = n & 255;
        ZXL[s*324 + k] = (k < 64) ? z[(kk*256 + b)*64 + k] : x[b*256 + (k - 64)];
    }
    for (int e = j; e < T_*16; e += 256) {
        int t = e >> 4, s = (e >> 1) & 7;
        int b = (blk*8 + s) & 255;
        FUT[e] = pred_seqs[b*1200 + t*24 + 20 + (e & 1)];
    }
    if (j < 16) {
        int b = (blk*8 + (j >> 1)) & 255;
        PRS[j] = inp_seqs[b*192 + 188 + (j & 1)];
    }
    __syncthreads();

    // ---- prologue: gates_const (4 tiles), h0, c0 via MFMA w/ packed frags
    const int R0 = U, R1 = 64+U, R2 = 128+U, R3 = 192+U;
    f32x4 gc[4], h0a, c0a;
    {
        float b0 = bih[R0]+bhh[R0], b1 = bih[R1]+bhh[R1];
        float b2 = bih[R2]+bhh[R2], b3 = bih[R3]+bhh[R3];
        gc[0] = (f32x4){b0,b0,b0,b0}; gc[1] = (f32x4){b1,b1,b1,b1};
        gc[2] = (f32x4){b2,b2,b2,b2}; gc[3] = (f32x4){b3,b3,b3,b3};
        float bh_ = bh0[U], bc_ = bc0[U];
        h0a = (f32x4){bh_,bh_,bh_,bh_};
        c0a = (f32x4){bc_,bc_,bc_,bc_};
    }
    for (int ks = 0; ks < 10; ++ks) {
        short8 ahi, alo;
        pack8(&ZXL[(c & 7)*324 + ks*32 + g*8], ahi, alo);
        #pragma unroll
        for (int q = 0; q < 4; ++q) {
            short8 Bh = WF[WIH_B + (((ks*4 + q)*2 + 0)*4 + w)*64 + l];
            short8 Bl = WF[WIH_B + (((ks*4 + q)*2 + 1)*4 + w)*64 + l];
            gc[q] = MFMA(ahi, Bh, gc[q]);
            gc[q] = MFMA(ahi, Bl, gc[q]);
            gc[q] = MFMA(alo, Bh, gc[q]);
        }
        {
            short8 Bh = WF[WH0_B + ((ks*2 + 0)*4 + w)*64 + l];
            short8 Bl = WF[WH0_B + ((ks*2 + 1)*4 + w)*64 + l];
            h0a = MFMA(ahi, Bh, h0a); h0a = MFMA(ahi, Bl, h0a); h0a = MFMA(alo, Bh, h0a);
        }
        {
            short8 Bh = WF[WC0_B + ((ks*2 + 0)*4 + w)*64 + l];
            short8 Bl = WF[WC0_B + ((ks*2 + 1)*4 + w)*64 + l];
            c0a = MFMA(ahi, Bh, c0a); c0a = MFMA(ahi, Bl, c0a); c0a = MFMA(alo, Bh, c0a);
        }
    }

    // assigned elements: g<2 -> acc rows 0,1 ; g>=2 -> rows 2,3
    const bool lowg = (g < 2);
    const int s0 = 4*(g & 1) + (lowg ? 0 : 2);     // first owned sample
    float cst0 = lowg ? c0a[0] : c0a[2];
    float cst1 = lowg ? c0a[1] : c0a[3];
    {
        float hv0 = lowg ? h0a[0] : h0a[2];
        float hv1 = lowg ? h0a[1] : h0a[3];
        unsigned short hh, ll;
        splitf(hv0, hh, ll); H0h[s0*72 + U] = hh; H0l[s0*72 + U] = ll;
        splitf(hv1, hh, ll); H0h[(s0+1)*72 + U] = hh; H0l[(s0+1)*72 + U] = ll;
    }

    // d-weights + Whh frags
    float wd0[4], wd1[4];
    wd0[0] = Wih[R0*322+320]; wd1[0] = Wih[R0*322+321];
    wd0[1] = Wih[R1*322+320]; wd1[1] = Wih[R1*322+321];
    wd0[2] = Wih[R2*322+320]; wd1[2] = Wih[R2*322+321];
    wd0[3] = Wih[R3*322+320]; wd1[3] = Wih[R3*322+321];
    short8 WB[4][2][2];
    #pragma unroll
    for (int q = 0; q < 4; ++q)
        #pragma unroll
        for (int ks = 0; ks < 2; ++ks)
            #pragma unroll
            for (int p = 0; p < 2; ++p)
                WB[q][ks][p] = WF[WHH_B + (((q*2 + ks)*2 + p)*4 + w)*64 + l];

    __syncthreads();   // H_0 visible

    const int nbase = blk*8;
    for (int t = 0; t < T_; ++t) {
        const unsigned short* Hh = (t & 1) ? H1h : H0h;
        const unsigned short* Hl = (t & 1) ? H1l : H0l;
        unsigned short* Nh = (t & 1) ? H0h : H1h;
        unsigned short* Nl = (t & 1) ? H0l : H1l;

        short8 ah0 = *reinterpret_cast<const short8*>(Hh + (c & 7)*72 + g*8);
        short8 al0 = *reinterpret_cast<const short8*>(Hl + (c & 7)*72 + g*8);
        short8 ah1 = *reinterpret_cast<const short8*>(Hh + (c & 7)*72 + 32 + g*8);
        short8 al1 = *reinterpret_cast<const short8*>(Hl + (c & 7)*72 + 32 + g*8);

        const float* dptr = (t == 0) ? PRS : (FUT + (t-1)*16);
        float2 dvr[4];
        #pragma unroll
        for (int r = 0; r < 4; ++r)
            dvr[r] = *reinterpret_cast<const float2*>(dptr + ((4*g + r) & 7)*2);

        f32x4 aq[4];
        #pragma unroll
        for (int q = 0; q < 4; ++q) {
            #pragma unroll
            for (int r = 0; r < 4; ++r)
                aq[q][r] = gc[q][r] + dvr[r].x*wd0[q] + dvr[r].y*wd1[q];
            aq[q] = MFMA(ah0, WB[q][0][0], aq[q]);
            aq[q] = MFMA(ah0, WB[q][0][1], aq[q]);
            aq[q] = MFMA(al0, WB[q][0][0], aq[q]);
            aq[q] = MFMA(ah1, WB[q][1][0], aq[q]);
            aq[q] = MFMA(ah1, WB[q][1][1], aq[q]);
            aq[q] = MFMA(al1, WB[q][1][0], aq[q]);
        }

        // cell for the lane's 2 owned (sample, U) elements
        float i0 = lowg ? aq[0][0] : aq[0][2], i1 = lowg ? aq[0][1] : aq[0][3];
        float f0 = lowg ? aq[1][0] : aq[1][2], f1 = lowg ? aq[1][1] : aq[1][3];
        float g0 = lowg ? aq[2][0] : aq[2][2], g1 = lowg ? aq[2][1] : aq[2][3];
        float o0 = lowg ? aq[3][0] : aq[3][2], o1 = lowg ? aq[3][1] : aq[3][3];
        float cc0 = sigf(f0)*cst0 + sigf(i0)*tanh_(g0); cst0 = cc0;
        float cc1 = sigf(f1)*cst1 + sigf(i1)*tanh_(g1); cst1 = cc1;
        float hv0 = sigf(o0)*tanh_(cc0);
        float hv1 = sigf(o1)*tanh_(cc1);

        unsigned short hh0, ll0, hh1, ll1;
        splitf(hv0, hh0, ll0);
        splitf(hv1, hh1, ll1);
        // global h (bf16 hi) for k2 — issue early, completes under LDS/barrier
        Hout[(size_t)(t*4096 + nbase + s0)*64 + U]     = hh0;
        Hout[(size_t)(t*4096 + nbase + s0 + 1)*64 + U] = hh1;
        Nh[s0*72 + U] = hh0;  Nl[s0*72 + U] = ll0;
        Nh[(s0+1)*72 + U] = hh1;  Nl[(s0+1)*72 + U] = ll1;
        __syncthreads();
    }
}

// ---------------- k2: proj + GMM ----------------
__launch_bounds__(256, 3)
__global__ void head_kernel(const float* __restrict__ pred_seqs,
                            const float* __restrict__ bpi, const float* __restrict__ bmu,
                            const float* __restrict__ bls, const float* __restrict__ bcorr,
                            const unsigned short* __restrict__ Hin,
                            const short8* __restrict__ WF,
                            float* __restrict__ out)
{
    __shared__ __align__(16) float PL[4][1600];   // per-wave 16 x 100
    const int j = threadIdx.x;
    const int w = j >> 6;
    const int l = j & 63;
    const int g = l >> 4;
    const int c = l & 15;
    const int blk = blockIdx.x;
    const int set = blk >> 2, chunk = blk & 3;
    const int t0 = (chunk*25) >> 1, t1 = ((chunk+1)*25) >> 1;

    float bias[6];
    #pragma unroll
    for (int pt = 0; pt < 6; ++pt) {
        int r3 = pt*16 + c;
        bias[pt] = (r3 < 16) ? bpi[r3] : (r3 < 48) ? bmu[r3-16]
                 : (r3 < 80) ? bls[r3-48] : bcorr[r3-80];
    }

    const int s = l >> 2, q4 = l & 3;
    const int n_s = set*16 + s, b_s = n_s & 255;
    float* PLw = &PL[w][0];
    float sum_local = 0.0f;

    for (int t = t0 + w; t < t1; t += 4) {
        const unsigned short* hp = Hin + (size_t)(t*4096 + set*16 + c)*64;
        short8 ah0 = *reinterpret_cast<const short8*>(hp + g*8);
        short8 ah1 = *reinterpret_cast<const short8*>(hp + 32 + g*8);
        #pragma unroll
        for (int pt = 0; pt < 6; ++pt) {
            short8 B00 = WF[PRJ_B + ((pt*2 + 0)*2 + 0)*64 + l];
            short8 B01 = WF[PRJ_B + ((pt*2 + 0)*2 + 1)*64 + l];
            short8 B10 = WF[PRJ_B + ((pt*2 + 1)*2 + 0)*64 + l];
            short8 B11 = WF[PRJ_B + ((pt*2 + 1)*2 + 1)*64 + l];
            f32x4 p = (f32x4){bias[pt], bias[pt], bias[pt], bias[pt]};
            p = MFMA(ah0, B00, p);
            p = MFMA(ah0, B01, p);
            p = MFMA(ah1, B10, p);
            p = MFMA(ah1, B11, p);
            #pragma unroll
            for (int r = 0; r < 4; ++r) PLw[(4*g + r)*100 + pt*16 + c] = p[r];
        }
        asm volatile("s_waitcnt lgkmcnt(0)" ::: "memory");
        __builtin_amdgcn_sched_barrier(0);

        float2 tv = *reinterpret_cast<const float2*>(pred_seqs + b_s*1200 + t*24 + 20);
        float a[4], m = -1e30f, Ppi = 0.0f;
        #pragma unroll
        for (int i = 0; i < 4; ++i) {
            int cq = q4*4 + i;
            float pi = PLw[s*100 + cq];
            float2 mu = *reinterpret_cast<const float2*>(PLw + s*100 + 16 + 2*cq);
            float2 ls = *reinterpret_cast<const float2*>(PLw + s*100 + 48 + 2*cq);
            float co = PLw[s*100 + 80 + cq];
            float l0 = fminf(fmaxf(ls.x, -10.0f), 10.0f);
            float l1 = fminf(fmaxf(ls.y, -10.0f), 10.0f);
            float z0 = (tv.x - mu.x) * __expf(-l0);
            float z1 = (tv.y - mu.y) * __expf(-l1);
            float ct = tanh_(co);
            float omr = 1.0f - ct*ct;
            float quad = z0*z0 + z1*z1 - 2.0f*ct*z0*z1;
            float comp = -1.8378770664093453f - (l0 + l1) - 0.5f*__logf(omr) - 0.5f*quad/omr;
            a[i] = pi + comp;
            m = fmaxf(m, a[i]);
            Ppi += __expf(pi);
        }
        m = fmaxf(m, __shfl_xor(m, 1));
        m = fmaxf(m, __shfl_xor(m, 2));
        float E = __expf(a[0]-m) + __expf(a[1]-m) + __expf(a[2]-m) + __expf(a[3]-m);
        E   += __shfl_xor(E, 1);   E   += __shfl_xor(E, 2);
        Ppi += __shfl_xor(Ppi, 1); Ppi += __shfl_xor(Ppi, 2);
        float logp = m + __logf(E) - __logf(Ppi);
        sum_local += fminf(logp, 50.0f);
    }
    if (q4 == 0) atomicAdd(out + n_s, sum_local);
}

extern "C" void kernel_launch(void* const* d_in, const int* in_sizes, int n_in,
                              void* d_out, int out_size, void* d_ws, size_t ws_size,
                              hipStream_t stream) {
    const float* x     = (const float*)d_in[0];
    const float* z     = (const float*)d_in[1];
    const float* iseq  = (const float*)d_in[2];
    const float* pseq  = (const float*)d_in[3];
    const float* Wh0   = (const float*)d_in[4];
    const float* bh0   = (const float*)d_in[5];
    const float* Wc0   = (const float*)d_in[6];
    const float* bc0   = (const float*)d_in[7];
    const float* Wih   = (const float*)d_in[8];
    const float* Whh   = (const float*)d_in[9];
    const float* bih   = (const float*)d_in[10];
    const float* bhh   = (const float*)d_in[11];
    const float* Wpi   = (const float*)d_in[12];
    const float* bpi   = (const float*)d_in[13];
    const float* Wmu   = (const float*)d_in[14];
    const float* bmu   = (const float*)d_in[15];
    const float* Wls   = (const float*)d_in[16];
    const float* bls   = (const float*)d_in[17];
    const float* Wcorr = (const float*)d_in[18];
    const float* bcorr = (const float*)d_in[19];
    float* out = (float*)d_out;

    unsigned short* Hbuf = (unsigned short*)d_ws;
    short8* WF = (short8*)((char*)d_ws + HBYTES);

    pack_kernel<<<71, 256, 0, stream>>>(Wih, Whh, Wh0, Wc0, Wpi, Wmu, Wls, Wcorr, WF);
    lstm_kernel<<<512, 256, 0, stream>>>(x, z, iseq, pseq, Wih, bh0, bc0, bih, bhh,
                                         Hbuf, (const short8*)WF);
    hipMemsetAsync(d_out, 0, 4096 * sizeof(float), stream);
    head_kernel<<<1024, 256, 0, stream>>>(pseq, bpi, bmu, bls, bcorr,
                                          (const unsigned short*)Hbuf,
                                          (const short8*)WF, out);
}